// Round 5
// baseline (52.678 us; speedup 1.0000x reference)
//
#include <hip/hip_runtime.h>
#include <math.h>

#define UNITS   512
#define BATCH   64
#define TIME    2048
#define LATENCY 60
#define ROWS    64     // bt-rows per block (main kernel)
#define THREADS 256
#define NROWS   (BATCH * TIME)

// ---------------- Kernel A: per-row precompute -> d_ws ----------------
// ws[bt] = {theta_deg, log2(speed), coh*0.01, 0}
__global__ __launch_bounds__(THREADS) void row_kernel(
    const float* __restrict__ inputs,    // (B,T,3)
    float4* __restrict__ ws)
{
    const int bt = blockIdx.x * THREADS + threadIdx.x;
    const int t  = bt & (TIME - 1);
    float vx = 0.0f, vy = 0.0f, c = 0.0f;
    if (t >= LATENCY) {
        vx = inputs[bt * 3 + 0];
        vy = inputs[bt * 3 + 1];
        c  = inputs[bt * 3 + 2];
    }
    const float speed = sqrtf(vx * vx + vy * vy);
    const float theta = atan2f(vx, vy) * 57.29577951308232f; // deg
    const float ls    = __log2f(speed);                      // -inf at 0
    ws[bt] = make_float4(theta, ls, c * 0.01f, 0.0f);
}

// ---------------- Kernel B: pure streaming writer ----------------
__global__ __launch_bounds__(THREADS) void mt_kernel(
    const float4* __restrict__ rowdata,   // (NROWS)
    const float* __restrict__ amp,        // (U)
    const float* __restrict__ baseline,   // (U)
    const float* __restrict__ thetapref,  // (U)
    const float* __restrict__ thetasig,   // (U)
    const float* __restrict__ speedpref,  // (U)
    const float* __restrict__ speedsig,   // (U)
    float* __restrict__ out)              // (B,T,U)
{
    const int tid   = threadIdx.x;
    const int rbase = blockIdx.x * ROWS;

    // ---- per-unit params: 4 consecutive units per thread, hoisted ----
    const int u0 = (tid & 127) * 4;
    const float4 tp  = *(const float4*)(thetapref + u0);
    const float4 tsg = *(const float4*)(thetasig  + u0);
    const float4 sp  = *(const float4*)(speedpref + u0);
    const float4 ssg = *(const float4*)(speedsig  + u0);
    const float4 am  = *(const float4*)(amp       + u0);
    const float4 bs  = *(const float4*)(baseline  + u0);

    const float L2E = 1.4426950408889634f;   // log2(e)
    // exp(-2 d^2/sig^2) = exp2(-d^2 * kd)
    float4 kd, ks, lsp;
    kd.x = 2.0f * L2E / (tsg.x * tsg.x);
    kd.y = 2.0f * L2E / (tsg.y * tsg.y);
    kd.z = 2.0f * L2E / (tsg.z * tsg.z);
    kd.w = 2.0f * L2E / (tsg.w * tsg.w);
    ks.x = 2.0f * L2E / (ssg.x * ssg.x);
    ks.y = 2.0f * L2E / (ssg.y * ssg.y);
    ks.z = 2.0f * L2E / (ssg.z * ssg.z);
    ks.w = 2.0f * L2E / (ssg.w * ssg.w);
    lsp.x = __log2f(sp.x);
    lsp.y = __log2f(sp.y);
    lsp.z = __log2f(sp.z);
    lsp.w = __log2f(sp.w);

    // ---- 32 iterations/thread, bounded unroll, pointer walk ----
    const int r0 = tid >> 7;                 // 0 or 1
    float4* p = (float4*)(out + (size_t)(rbase + r0) * UNITS + u0);
    const int pstride = (2 * UNITS) / 4;     // float4s per 2 rows
    const float4* rp = rowdata + rbase + r0;

    #pragma unroll 2
    for (int r = r0; r < ROWS; r += 2, p += pstride, rp += 2) {
        const float4 rv    = *rp;            // wave-uniform -> broadcast, L2-hot
        const float  theta = rv.x;
        const float  ls    = rv.y;
        const float  coh   = rv.z;

        float4 o;
        {
            const float d = theta - tp.x, l = ls - lsp.x;
            const float e = fmaf(l * l, ks.x, d * d * kd.x);
            o.x = fmaf(am.x * coh, exp2f(-e), bs.x);
        }
        {
            const float d = theta - tp.y, l = ls - lsp.y;
            const float e = fmaf(l * l, ks.y, d * d * kd.y);
            o.y = fmaf(am.y * coh, exp2f(-e), bs.y);
        }
        {
            const float d = theta - tp.z, l = ls - lsp.z;
            const float e = fmaf(l * l, ks.z, d * d * kd.z);
            o.z = fmaf(am.z * coh, exp2f(-e), bs.z);
        }
        {
            const float d = theta - tp.w, l = ls - lsp.w;
            const float e = fmaf(l * l, ks.w, d * d * kd.w);
            o.w = fmaf(am.w * coh, exp2f(-e), bs.w);
        }

        *p = o;
    }
}

extern "C" void kernel_launch(void* const* d_in, const int* in_sizes, int n_in,
                              void* d_out, int out_size, void* d_ws, size_t ws_size,
                              hipStream_t stream) {
    const float* inputs    = (const float*)d_in[0];
    const float* amp       = (const float*)d_in[1];
    const float* baseline  = (const float*)d_in[2];
    const float* thetapref = (const float*)d_in[3];
    const float* thetasig  = (const float*)d_in[4];
    const float* speedpref = (const float*)d_in[5];
    const float* speedsig  = (const float*)d_in[6];
    float* out = (float*)d_out;
    float4* ws = (float4*)d_ws;              // 131072 * 16 B = 2 MB

    row_kernel<<<dim3(NROWS / THREADS), dim3(THREADS), 0, stream>>>(inputs, ws);
    mt_kernel<<<dim3(NROWS / ROWS), dim3(THREADS), 0, stream>>>(
        ws, amp, baseline, thetapref, thetasig, speedpref, speedsig, out);
}

// Round 6
// 47.835 us; speedup vs baseline: 1.1012x; 1.1012x over previous
//
#include <hip/hip_runtime.h>
#include <math.h>

#define UNITS   512
#define BATCH   64
#define TIME    2048
#define LATENCY 60
#define ROWS    64     // bt-rows per block
#define THREADS 256

__global__ __launch_bounds__(THREADS) void mt_kernel(
    const float* __restrict__ inputs,     // (B,T,3)
    const float* __restrict__ amp,        // (U)
    const float* __restrict__ baseline,   // (U)
    const float* __restrict__ thetapref,  // (U)
    const float* __restrict__ thetasig,   // (U)
    const float* __restrict__ speedpref,  // (U)
    const float* __restrict__ speedsig,   // (U)
    float* __restrict__ out)              // (B,T,U)
{
    __shared__ float4 row[ROWS];          // {theta_deg, log2(speed), coh, -}
    const int tid   = threadIdx.x;
    const int rbase = blockIdx.x * ROWS;

    // ---- Phase A: per-row quantities (64 rows, one thread each) ----
    if (tid < ROWS) {
        const int bt = rbase + tid;
        const int t  = bt & (TIME - 1);
        float vx = 0.0f, vy = 0.0f, c = 0.0f;
        if (t >= LATENCY) {
            vx = inputs[bt * 3 + 0];
            vy = inputs[bt * 3 + 1];
            c  = inputs[bt * 3 + 2];
        }
        const float speed = sqrtf(vx * vx + vy * vy);
        const float theta = atan2f(vx, vy) * 57.29577951308232f; // deg
        const float ls    = __log2f(speed);                      // -inf at 0
        row[tid] = make_float4(theta, ls, c * 0.01f, 0.0f);
    }

    // ---- per-unit params: 4 consecutive units per thread, hoisted ----
    const int u0 = (tid & 127) * 4;
    const float4 tp  = *(const float4*)(thetapref + u0);
    const float4 tsg = *(const float4*)(thetasig  + u0);
    const float4 sp  = *(const float4*)(speedpref + u0);
    const float4 ssg = *(const float4*)(speedsig  + u0);
    const float4 am  = *(const float4*)(amp       + u0);
    const float4 bs  = *(const float4*)(baseline  + u0);

    const float L2E = 1.4426950408889634f;   // log2(e)
    // exp(-2 d^2/sig^2) = exp2(-d^2 * kd)
    float4 kd, ks, lsp;
    kd.x = 2.0f * L2E / (tsg.x * tsg.x);
    kd.y = 2.0f * L2E / (tsg.y * tsg.y);
    kd.z = 2.0f * L2E / (tsg.z * tsg.z);
    kd.w = 2.0f * L2E / (tsg.w * tsg.w);
    ks.x = 2.0f * L2E / (ssg.x * ssg.x);
    ks.y = 2.0f * L2E / (ssg.y * ssg.y);
    ks.z = 2.0f * L2E / (ssg.z * ssg.z);
    ks.w = 2.0f * L2E / (ssg.w * ssg.w);
    lsp.x = __log2f(sp.x);
    lsp.y = __log2f(sp.y);
    lsp.z = __log2f(sp.z);
    lsp.w = __log2f(sp.w);

    __syncthreads();

    // ---- Phase B: 32 iterations/thread, unroll 4, pointer walk ----
    const int r0 = tid >> 7;                 // 0 or 1
    float4* p = (float4*)(out + (size_t)(rbase + r0) * UNITS + u0);
    const int pstride = (2 * UNITS) / 4;     // float4s per 2 rows

    #pragma unroll 4
    for (int r = r0; r < ROWS; r += 2, p += pstride) {
        const float4 rv    = row[r];
        const float  theta = rv.x;
        const float  ls    = rv.y;
        const float  coh   = rv.z;

        float4 o;
        {
            const float d = theta - tp.x, l = ls - lsp.x;
            const float e = fmaf(l * l, ks.x, d * d * kd.x);
            o.x = fmaf(am.x * coh, exp2f(-e), bs.x);
        }
        {
            const float d = theta - tp.y, l = ls - lsp.y;
            const float e = fmaf(l * l, ks.y, d * d * kd.y);
            o.y = fmaf(am.y * coh, exp2f(-e), bs.y);
        }
        {
            const float d = theta - tp.z, l = ls - lsp.z;
            const float e = fmaf(l * l, ks.z, d * d * kd.z);
            o.z = fmaf(am.z * coh, exp2f(-e), bs.z);
        }
        {
            const float d = theta - tp.w, l = ls - lsp.w;
            const float e = fmaf(l * l, ks.w, d * d * kd.w);
            o.w = fmaf(am.w * coh, exp2f(-e), bs.w);
        }

        *p = o;
    }
}

extern "C" void kernel_launch(void* const* d_in, const int* in_sizes, int n_in,
                              void* d_out, int out_size, void* d_ws, size_t ws_size,
                              hipStream_t stream) {
    const float* inputs    = (const float*)d_in[0];
    const float* amp       = (const float*)d_in[1];
    const float* baseline  = (const float*)d_in[2];
    const float* thetapref = (const float*)d_in[3];
    const float* thetasig  = (const float*)d_in[4];
    const float* speedpref = (const float*)d_in[5];
    const float* speedsig  = (const float*)d_in[6];
    float* out = (float*)d_out;

    const int nrows = BATCH * TIME;          // 131072
    dim3 grid(nrows / ROWS);                 // 2048 blocks
    dim3 block(THREADS);
    mt_kernel<<<grid, block, 0, stream>>>(inputs, amp, baseline, thetapref,
                                          thetasig, speedpref, speedsig, out);
}